// Round 1
// baseline (552.420 us; speedup 1.0000x reference)
//
#include <hip/hip_runtime.h>

#define NN   50000
#define FIN  256
#define HD   128
#define CC   64
#define KK   4
#define RWSS 16
#define NRW  (NN*RWSS)          // 800000
#define KNRW (KK*NRW)           // 3200000

// ---------------------------------------------------------------------------
// Linear: out[n][j] = sum_f A[n][f]*W[j][f] + b[j]   (W row-major [128][DIN])
// Tile: 64 rows x 128 cols per block, 256 threads, 8x4 acc per thread.
// ---------------------------------------------------------------------------
template<int DIN>
__global__ __launch_bounds__(256) void linear_kernel(
    const float* __restrict__ A, const float* __restrict__ W,
    const float* __restrict__ bias, float* __restrict__ outp, int n)
{
    __shared__ float As[32][68];    // f-major, padded (68%32=4, 16B-aligned rows)
    __shared__ float Ws[32][132];   // f-major, padded
    const int tid = threadIdx.x;
    const int r0  = blockIdx.x * 64;
    const int tc  = tid & 31;       // col group -> cols 4*tc..4*tc+3
    const int tr  = tid >> 5;       // row group -> rows 8*tr..8*tr+7
    float acc[8][4];
#pragma unroll
    for (int r = 0; r < 8; ++r)
#pragma unroll
        for (int c = 0; c < 4; ++c) acc[r][c] = 0.f;

    for (int f0 = 0; f0 < DIN; f0 += 32) {
        // stage A tile (transpose to f-major)
        {
            const int rr = tid >> 3;          // 0..31
            const int fo = (tid & 7) << 2;    // 0,4,...,28
#pragma unroll
            for (int hh = 0; hh < 2; ++hh) {
                const int row = rr + 32 * hh;
                const int gr  = r0 + row;
                float4 v = make_float4(0.f, 0.f, 0.f, 0.f);
                if (gr < n) v = *(const float4*)(A + (size_t)gr * DIN + f0 + fo);
                As[fo + 0][row] = v.x; As[fo + 1][row] = v.y;
                As[fo + 2][row] = v.z; As[fo + 3][row] = v.w;
            }
        }
        // stage W tile (transpose to f-major)
        {
            const int col = tid >> 1;         // 0..127
            const int fb  = (tid & 1) << 4;   // 0 or 16
#pragma unroll
            for (int q = 0; q < 4; ++q) {
                const int fo = fb + (q << 2);
                float4 v = *(const float4*)(W + (size_t)col * DIN + f0 + fo);
                Ws[fo + 0][col] = v.x; Ws[fo + 1][col] = v.y;
                Ws[fo + 2][col] = v.z; Ws[fo + 3][col] = v.w;
            }
        }
        __syncthreads();
#pragma unroll
        for (int ft = 0; ft < 32; ++ft) {
            const float4 wv = *(const float4*)&Ws[ft][tc << 2];
            const float4 a0 = *(const float4*)&As[ft][tr << 3];
            const float4 a1 = *(const float4*)&As[ft][(tr << 3) + 4];
            const float av[8] = {a0.x, a0.y, a0.z, a0.w, a1.x, a1.y, a1.z, a1.w};
            const float wl[4] = {wv.x, wv.y, wv.z, wv.w};
#pragma unroll
            for (int r = 0; r < 8; ++r)
#pragma unroll
                for (int c = 0; c < 4; ++c)
                    acc[r][c] = fmaf(av[r], wl[c], acc[r][c]);
        }
        __syncthreads();
    }
    const float4 bv = *(const float4*)(bias + (tc << 2));
    const float bl[4] = {bv.x, bv.y, bv.z, bv.w};
#pragma unroll
    for (int r = 0; r < 8; ++r) {
        const int gr = r0 + (tr << 3) + r;
        if (gr < n) {
            float4 o;
            o.x = acc[r][0] + bl[0]; o.y = acc[r][1] + bl[1];
            o.z = acc[r][2] + bl[2]; o.w = acc[r][3] + bl[3];
            *(float4*)(outp + (size_t)gr * HD + (tc << 2)) = o;
        }
    }
}

// ---------------------------------------------------------------------------
// al[n] = h[n]·alw + alb ; ar[n] = h[n]·arw + arb.  One wave per node.
// ---------------------------------------------------------------------------
__global__ __launch_bounds__(256) void att_kernel(
    const float* __restrict__ h,
    const float* __restrict__ alw, const float* __restrict__ alb,
    const float* __restrict__ arw, const float* __restrict__ arb,
    float* __restrict__ al, float* __restrict__ ar, int n)
{
    const int lane = threadIdx.x & 63;
    const int w    = threadIdx.x >> 6;
    const int node = blockIdx.x * 4 + w;
    if (node >= n) return;
    const float h0 = h[(size_t)node * HD + lane];
    const float h1 = h[(size_t)node * HD + 64 + lane];
    float a = h0 * alw[lane] + h1 * alw[64 + lane];
    float b = h0 * arw[lane] + h1 * arw[64 + lane];
#pragma unroll
    for (int o = 32; o >= 1; o >>= 1) {
        a += __shfl_xor(a, o, 64);
        b += __shfl_xor(b, o, 64);
    }
    if (lane == 0) {
        al[node] = a + alb[0];
        ar[node] = b + arb[0];
    }
}

// ---------------------------------------------------------------------------
// Aggregation: one block (128 threads) per node; thread = feature channel.
// Wave 0's 64 lanes compute all 4 hops' 16-way softmaxes (k = lane>>4).
// ---------------------------------------------------------------------------
__global__ __launch_bounds__(128) void aggr_kernel(
    const float* __restrict__ h, const float* __restrict__ al,
    const float* __restrict__ ar, const int* __restrict__ ends_l,
    const float* __restrict__ att_l, float* __restrict__ outp, int n)
{
    const int node = blockIdx.x;
    const int c    = threadIdx.x;
    __shared__ float w_s[KK][RWSS];
    __shared__ int   e_s[KK][RWSS];
    if (c < 64) {
        const int k = c >> 4;
        const int j = c & 15;
        const int e = ends_l[k * NRW + node * RWSS + j];
        float lg = al[node] + ar[e];
        lg = (lg > 0.f) ? lg : 0.2f * lg;
        float m = lg;
#pragma unroll
        for (int o = 8; o >= 1; o >>= 1) m = fmaxf(m, __shfl_xor(m, o, 16));
        const float ex = __expf(lg - m);
        float s = ex;
#pragma unroll
        for (int o = 8; o >= 1; o >>= 1) s += __shfl_xor(s, o, 16);
        w_s[k][j] = ex / s * att_l[k + 1] * (1.0f / RWSS);
        e_s[k][j] = e;
    }
    float acc = att_l[0] * h[(size_t)node * HD + c];
    __syncthreads();
#pragma unroll
    for (int k = 0; k < KK; ++k) {
#pragma unroll
        for (int j = 0; j < RWSS; ++j) {
            acc = fmaf(w_s[k][j], h[(size_t)e_s[k][j] * HD + c], acc);
        }
    }
    outp[(size_t)node * HD + c] = acc;
}

// ---------------------------------------------------------------------------
// out = log_softmax(h @ lout_w^T + lout_b).  One wave per node (C=64 lanes).
// ---------------------------------------------------------------------------
__global__ __launch_bounds__(256) void out_kernel(
    const float* __restrict__ hin, const float* __restrict__ lw,
    const float* __restrict__ lb, float* __restrict__ outp, int n)
{
    __shared__ float ws[HD][CC + 1];   // ws[f][c]
    __shared__ float hs[4][HD];
    const int tid = threadIdx.x;
    for (int i = tid; i < CC * HD; i += 256) {
        const int ccol = i >> 7;
        const int ff   = i & 127;
        ws[ff][ccol] = lw[i];
    }
    const int w    = tid >> 6;
    const int lane = tid & 63;
    const int node = blockIdx.x * 4 + w;
    if (node < n) {
        hs[w][lane]      = hin[(size_t)node * HD + lane];
        hs[w][lane + 64] = hin[(size_t)node * HD + 64 + lane];
    }
    __syncthreads();
    if (node >= n) return;
    float acc = lb[lane];
#pragma unroll 8
    for (int f = 0; f < HD; ++f)
        acc = fmaf(hs[w][f], ws[f][lane], acc);
    float m = acc;
#pragma unroll
    for (int o = 32; o >= 1; o >>= 1) m = fmaxf(m, __shfl_xor(m, o, 64));
    const float ex = __expf(acc - m);
    float s = ex;
#pragma unroll
    for (int o = 32; o >= 1; o >>= 1) s += __shfl_xor(s, o, 64);
    outp[(size_t)node * CC + lane] = acc - m - __logf(s);
}

// ---------------------------------------------------------------------------
extern "C" void kernel_launch(void* const* d_in, const int* in_sizes, int n_in,
                              void* d_out, int out_size, void* d_ws, size_t ws_size,
                              hipStream_t stream)
{
    const float* x      = (const float*)d_in[0];
    const int*   ends   = (const int*)  d_in[1];
    const float* lin0_w = (const float*)d_in[2];
    const float* lin0_b = (const float*)d_in[3];
    const float* lin1_w = (const float*)d_in[4];
    const float* lin1_b = (const float*)d_in[5];
    const float* lout_w = (const float*)d_in[6];
    const float* lout_b = (const float*)d_in[7];
    const float* attl_w = (const float*)d_in[8];
    const float* attl_b = (const float*)d_in[9];
    const float* attr_w = (const float*)d_in[10];
    const float* attr_b = (const float*)d_in[11];
    const float* att    = (const float*)d_in[12];
    float* outp = (float*)d_out;

    float* hbuf   = (float*)d_ws;                 // 50000*128
    float* aggbuf = hbuf + (size_t)NN * HD;       // 50000*128
    float* albuf  = aggbuf + (size_t)NN * HD;     // 50000
    float* arbuf  = albuf + NN;                   // 50000

    const int lin_grid = (NN + 63) / 64;

    // ---- layer 0 ----
    linear_kernel<FIN><<<lin_grid, 256, 0, stream>>>(x, lin0_w, lin0_b, hbuf, NN);
    att_kernel<<<(NN + 3) / 4, 256, 0, stream>>>(hbuf, attl_w, attl_b, attr_w, attr_b,
                                                 albuf, arbuf, NN);
    aggr_kernel<<<NN, 128, 0, stream>>>(hbuf, albuf, arbuf, ends, att, aggbuf, NN);

    // ---- layer 1 ----
    linear_kernel<HD><<<lin_grid, 256, 0, stream>>>(aggbuf, lin1_w, lin1_b, hbuf, NN);
    att_kernel<<<(NN + 3) / 4, 256, 0, stream>>>(hbuf, attl_w + HD, attl_b + 1,
                                                 attr_w + HD, attr_b + 1,
                                                 albuf, arbuf, NN);
    aggr_kernel<<<NN, 128, 0, stream>>>(hbuf, albuf, arbuf, ends + KNRW, att + (KK + 1),
                                        aggbuf, NN);

    // ---- output head ----
    out_kernel<<<(NN + 3) / 4, 256, 0, stream>>>(aggbuf, lout_w, lout_b, outp, NN);
}

// Round 2
// 332.154 us; speedup vs baseline: 1.6631x; 1.6631x over previous
//
#include <hip/hip_runtime.h>
#include <hip/hip_bf16.h>

#define NN   50000
#define FIN  256
#define HD   128
#define CC   64
#define KK   4
#define RWSS 16
#define NRW  (NN*RWSS)          // 800000
#define KNRW (KK*NRW)           // 3200000

typedef unsigned int   uint32;
typedef unsigned short ushort_t;

static __device__ __forceinline__ float bf16lo(uint32 u) {
    return __uint_as_float(u << 16);
}
static __device__ __forceinline__ float bf16hi(uint32 u) {
    return __uint_as_float(u & 0xFFFF0000u);
}
static __device__ __forceinline__ ushort_t f2bf16(float f) {
    uint32 u = __float_as_uint(f);
    uint32 r = u + 0x7FFFu + ((u >> 16) & 1u);   // RNE
    return (ushort_t)(r >> 16);
}

// ---------------------------------------------------------------------------
// Linear: h16[n][j] = bf16( sum_f A[n][f]*W[j][f] + b[j] )
// Tile: 64 rows x 128 cols per block, 256 threads, 8x4 acc per thread.
// ---------------------------------------------------------------------------
template<int DIN>
__global__ __launch_bounds__(256) void linear_kernel(
    const float* __restrict__ A, const float* __restrict__ W,
    const float* __restrict__ bias, ushort_t* __restrict__ out16, int n)
{
    __shared__ float As[32][68];    // f-major, padded
    __shared__ float Ws[32][132];   // f-major, padded
    const int tid = threadIdx.x;
    const int r0  = blockIdx.x * 64;
    const int tc  = tid & 31;       // col group -> cols 4*tc..4*tc+3
    const int tr  = tid >> 5;       // row group -> rows 8*tr..8*tr+7
    float acc[8][4];
#pragma unroll
    for (int r = 0; r < 8; ++r)
#pragma unroll
        for (int c = 0; c < 4; ++c) acc[r][c] = 0.f;

    for (int f0 = 0; f0 < DIN; f0 += 32) {
        {
            const int rr = tid >> 3;          // 0..31
            const int fo = (tid & 7) << 2;    // 0,4,...,28
#pragma unroll
            for (int hh = 0; hh < 2; ++hh) {
                const int row = rr + 32 * hh;
                const int gr  = r0 + row;
                float4 v = make_float4(0.f, 0.f, 0.f, 0.f);
                if (gr < n) v = *(const float4*)(A + (size_t)gr * DIN + f0 + fo);
                As[fo + 0][row] = v.x; As[fo + 1][row] = v.y;
                As[fo + 2][row] = v.z; As[fo + 3][row] = v.w;
            }
        }
        {
            const int col = tid >> 1;         // 0..127
            const int fb  = (tid & 1) << 4;   // 0 or 16
#pragma unroll
            for (int q = 0; q < 4; ++q) {
                const int fo = fb + (q << 2);
                float4 v = *(const float4*)(W + (size_t)col * DIN + f0 + fo);
                Ws[fo + 0][col] = v.x; Ws[fo + 1][col] = v.y;
                Ws[fo + 2][col] = v.z; Ws[fo + 3][col] = v.w;
            }
        }
        __syncthreads();
#pragma unroll
        for (int ft = 0; ft < 32; ++ft) {
            const float4 wv = *(const float4*)&Ws[ft][tc << 2];
            const float4 a0 = *(const float4*)&As[ft][tr << 3];
            const float4 a1 = *(const float4*)&As[ft][(tr << 3) + 4];
            const float av[8] = {a0.x, a0.y, a0.z, a0.w, a1.x, a1.y, a1.z, a1.w};
            const float wl[4] = {wv.x, wv.y, wv.z, wv.w};
#pragma unroll
            for (int r = 0; r < 8; ++r)
#pragma unroll
                for (int c = 0; c < 4; ++c)
                    acc[r][c] = fmaf(av[r], wl[c], acc[r][c]);
        }
        __syncthreads();
    }
    const float4 bv = *(const float4*)(bias + (tc << 2));
    const float bl[4] = {bv.x, bv.y, bv.z, bv.w};
#pragma unroll
    for (int r = 0; r < 8; ++r) {
        const int gr = r0 + (tr << 3) + r;
        if (gr < n) {
            ushort4 o;
            o.x = f2bf16(acc[r][0] + bl[0]);
            o.y = f2bf16(acc[r][1] + bl[1]);
            o.z = f2bf16(acc[r][2] + bl[2]);
            o.w = f2bf16(acc[r][3] + bl[3]);
            *(ushort4*)(out16 + (size_t)gr * HD + (tc << 2)) = o;
        }
    }
}

// ---------------------------------------------------------------------------
// al[n] = h[n]·alw + alb ; ar[n] = h[n]·arw + arb.  One wave per node.
// Grid is exact (50000/4), no bounds checks.
// ---------------------------------------------------------------------------
__global__ __launch_bounds__(256) void att_kernel(
    const ushort_t* __restrict__ h16,
    const float* __restrict__ alw, const float* __restrict__ alb,
    const float* __restrict__ arw, const float* __restrict__ arb,
    float* __restrict__ al, float* __restrict__ ar)
{
    const int lane = threadIdx.x & 63;
    const int node = blockIdx.x * 4 + (threadIdx.x >> 6);
    const uint32 v = ((const uint32*)h16)[(size_t)node * (HD / 2) + lane];
    const float x0 = bf16lo(v), x1 = bf16hi(v);
    const float2 wl = ((const float2*)alw)[lane];
    const float2 wr = ((const float2*)arw)[lane];
    float a = x0 * wl.x + x1 * wl.y;
    float b = x0 * wr.x + x1 * wr.y;
#pragma unroll
    for (int o = 32; o >= 1; o >>= 1) {
        a += __shfl_xor(a, o, 64);
        b += __shfl_xor(b, o, 64);
    }
    if (lane == 0) {
        al[node] = a + alb[0];
        ar[node] = b + arb[0];
    }
}

// ---------------------------------------------------------------------------
// Aggregation: one wave per node (block = 4 nodes). All 64 lanes compute the
// 4 hops' 16-way softmaxes (k = lane>>4, j = lane&15); then each lane
// accumulates 2 channels from packed bf16x2 gathers.
// ---------------------------------------------------------------------------
__global__ __launch_bounds__(256) void aggr_kernel(
    const ushort_t* __restrict__ h16, const float* __restrict__ al,
    const float* __restrict__ ar, const int* __restrict__ ends_l,
    const float* __restrict__ att_l, float* __restrict__ outp)
{
    __shared__ float w_s[4][64];
    __shared__ int   e_s[4][64];
    const int w    = threadIdx.x >> 6;
    const int lane = threadIdx.x & 63;
    const int node = blockIdx.x * 4 + w;
    const int k    = lane >> 4;
    const int j    = lane & 15;

    const int e = ends_l[(size_t)k * NRW + node * RWSS + j];
    float lg = al[node] + ar[e];
    lg = (lg > 0.f) ? lg : 0.2f * lg;
    float m = lg;
#pragma unroll
    for (int o = 8; o >= 1; o >>= 1) m = fmaxf(m, __shfl_xor(m, o, 16));
    const float ex = __expf(lg - m);
    float s = ex;
#pragma unroll
    for (int o = 8; o >= 1; o >>= 1) s += __shfl_xor(s, o, 16);
    w_s[w][lane] = ex / s * att_l[k + 1] * (1.0f / RWSS);
    e_s[w][lane] = e;
    __syncthreads();

    const uint32* hp = (const uint32*)h16;
    const uint32 vs = hp[(size_t)node * (HD / 2) + lane];
    const float att0 = att_l[0];
    float a0 = bf16lo(vs) * att0;
    float a1 = bf16hi(vs) * att0;
#pragma unroll
    for (int i = 0; i < 64; ++i) {
        const int   ei = e_s[w][i];
        const float wi = w_s[w][i];
        const uint32 v = hp[(size_t)ei * (HD / 2) + lane];
        a0 = fmaf(bf16lo(v), wi, a0);
        a1 = fmaf(bf16hi(v), wi, a1);
    }
    float2 o; o.x = a0; o.y = a1;
    ((float2*)outp)[(size_t)node * (HD / 2) + lane] = o;
}

// ---------------------------------------------------------------------------
// out = log_softmax(h @ lout_w^T + lout_b).  One wave per node (C=64 lanes).
// ---------------------------------------------------------------------------
__global__ __launch_bounds__(256) void out_kernel(
    const float* __restrict__ hin, const float* __restrict__ lw,
    const float* __restrict__ lb, float* __restrict__ outp)
{
    __shared__ float ws[HD][CC + 1];   // ws[f][c]
    __shared__ float hs[4][HD];
    const int tid = threadIdx.x;
    for (int i = tid; i < CC * HD; i += 256) {
        const int ccol = i >> 7;
        const int ff   = i & 127;
        ws[ff][ccol] = lw[i];
    }
    const int w    = tid >> 6;
    const int lane = tid & 63;
    const int node = blockIdx.x * 4 + w;
    hs[w][lane]      = hin[(size_t)node * HD + lane];
    hs[w][lane + 64] = hin[(size_t)node * HD + 64 + lane];
    __syncthreads();
    float acc = lb[lane];
#pragma unroll 8
    for (int f = 0; f < HD; ++f)
        acc = fmaf(hs[w][f], ws[f][lane], acc);
    float m = acc;
#pragma unroll
    for (int o = 32; o >= 1; o >>= 1) m = fmaxf(m, __shfl_xor(m, o, 64));
    const float ex = __expf(acc - m);
    float s = ex;
#pragma unroll
    for (int o = 32; o >= 1; o >>= 1) s += __shfl_xor(s, o, 64);
    outp[(size_t)node * CC + lane] = acc - m - __logf(s);
}

// ---------------------------------------------------------------------------
extern "C" void kernel_launch(void* const* d_in, const int* in_sizes, int n_in,
                              void* d_out, int out_size, void* d_ws, size_t ws_size,
                              hipStream_t stream)
{
    const float* x      = (const float*)d_in[0];
    const int*   ends   = (const int*)  d_in[1];
    const float* lin0_w = (const float*)d_in[2];
    const float* lin0_b = (const float*)d_in[3];
    const float* lin1_w = (const float*)d_in[4];
    const float* lin1_b = (const float*)d_in[5];
    const float* lout_w = (const float*)d_in[6];
    const float* lout_b = (const float*)d_in[7];
    const float* attl_w = (const float*)d_in[8];
    const float* attl_b = (const float*)d_in[9];
    const float* attr_w = (const float*)d_in[10];
    const float* attr_b = (const float*)d_in[11];
    const float* att    = (const float*)d_in[12];
    float* outp = (float*)d_out;

    // workspace layout
    ushort_t* h16    = (ushort_t*)d_ws;                    // 50000*128 bf16 (12.8MB)
    float*    aggbuf = (float*)(h16 + (size_t)NN * HD);    // 50000*128 f32  (25.6MB)
    float*    albuf  = aggbuf + (size_t)NN * HD;           // 50000
    float*    arbuf  = albuf + NN;                         // 50000

    const int lin_grid = (NN + 63) / 64;
    const int nb4      = NN / 4;   // 12500, exact

    // ---- layer 0 ----
    linear_kernel<FIN><<<lin_grid, 256, 0, stream>>>(x, lin0_w, lin0_b, h16, NN);
    att_kernel<<<nb4, 256, 0, stream>>>(h16, attl_w, attl_b, attr_w, attr_b,
                                        albuf, arbuf);
    aggr_kernel<<<nb4, 256, 0, stream>>>(h16, albuf, arbuf, ends, att, aggbuf);

    // ---- layer 1 ----
    linear_kernel<HD><<<lin_grid, 256, 0, stream>>>(aggbuf, lin1_w, lin1_b, h16, NN);
    att_kernel<<<nb4, 256, 0, stream>>>(h16, attl_w + HD, attl_b + 1,
                                        attr_w + HD, attr_b + 1, albuf, arbuf);
    aggr_kernel<<<nb4, 256, 0, stream>>>(h16, albuf, arbuf, ends + KNRW,
                                         att + (KK + 1), aggbuf);

    // ---- output head ----
    out_kernel<<<nb4, 256, 0, stream>>>(aggbuf, lout_w, lout_b, outp);
}

// Round 3
// 280.473 us; speedup vs baseline: 1.9696x; 1.1843x over previous
//
#include <hip/hip_runtime.h>
#include <hip/hip_bf16.h>

#define NN   50000
#define FIN  256
#define HD   128
#define CC   64
#define KK   4
#define RWSS 16
#define NRW  (NN*RWSS)          // 800000
#define KNRW (KK*NRW)           // 3200000

typedef unsigned int   uint32;
typedef unsigned short ushort_t;

typedef __attribute__((ext_vector_type(8))) short short8v;   // 8 bf16 (4 VGPR)
typedef __attribute__((ext_vector_type(4))) float float4v;   // MFMA acc

static __device__ __forceinline__ float bf16lo(uint32 u) {
    return __uint_as_float(u << 16);
}
static __device__ __forceinline__ float bf16hi(uint32 u) {
    return __uint_as_float(u & 0xFFFF0000u);
}
static __device__ __forceinline__ ushort_t f2bf16(float f) {
    uint32 u = __float_as_uint(f);
    uint32 r = u + 0x7FFFu + ((u >> 16) & 1u);   // RNE
    return (ushort_t)(r >> 16);
}

// ---------------------------------------------------------------------------
// MFMA linear + fused attention projections.
// Block = 256 thr = 4 waves; wave owns 16 rows x 128 cols.
// W staged to LDS as bf16 in [k8][j] 16B chunks (k-major within chunk).
// A-fragments straight from global (fp32->bf16 cvt for layer 0).
// Epilogue: h = acc + b -> bf16 store; al/ar = h . alw/arw via 16-lane reduce.
// ---------------------------------------------------------------------------
template<int DIN, bool ABF16>
__global__ __launch_bounds__(256) void linear_mfma_kernel(
    const void* __restrict__ Ain, const float* __restrict__ W,
    const float* __restrict__ bias,
    const float* __restrict__ alw, const float* __restrict__ alb,
    const float* __restrict__ arw, const float* __restrict__ arb,
    ushort_t* __restrict__ out16, float* __restrict__ al, float* __restrict__ ar)
{
    __shared__ uint4 Wl[(DIN / 8) * 128];        // bf16 W, [k8][j] 16B chunks
    const int tid  = threadIdx.x;
    const int wid  = tid >> 6;
    const int lane = tid & 63;

    // ---- stage W (fp32 -> bf16) ----
    for (int idx = tid; idx < (DIN / 8) * 128; idx += 256) {
        const int jj = idx & 127;
        const int k8 = idx >> 7;
        const float4 w0 = *(const float4*)(W + (size_t)jj * DIN + 8 * k8);
        const float4 w1 = *(const float4*)(W + (size_t)jj * DIN + 8 * k8 + 4);
        uint4 p;
        p.x = (uint32)f2bf16(w0.x) | ((uint32)f2bf16(w0.y) << 16);
        p.y = (uint32)f2bf16(w0.z) | ((uint32)f2bf16(w0.w) << 16);
        p.z = (uint32)f2bf16(w1.x) | ((uint32)f2bf16(w1.y) << 16);
        p.w = (uint32)f2bf16(w1.z) | ((uint32)f2bf16(w1.w) << 16);
        Wl[idx] = p;
    }
    __syncthreads();

    const int mrow = lane & 15;          // A-row (and B-col) index within tile
    const int kq   = lane >> 4;          // k-quarter
    const int row  = blockIdx.x * 64 + wid * 16 + mrow;
    const int arow = row < NN ? row : NN - 1;

    float4v acc[8];
#pragma unroll
    for (int t = 0; t < 8; ++t) acc[t] = (float4v){0.f, 0.f, 0.f, 0.f};

    for (int f0 = 0; f0 < DIN; f0 += 32) {
        short8v a;
        if constexpr (ABF16) {
            a = *(const short8v*)((const ushort_t*)Ain + (size_t)arow * DIN + f0 + 8 * kq);
        } else {
            const float* ap = (const float*)Ain + (size_t)arow * DIN + f0 + 8 * kq;
            const float4 a0 = *(const float4*)ap;
            const float4 a1 = *(const float4*)(ap + 4);
            a[0] = (short)f2bf16(a0.x); a[1] = (short)f2bf16(a0.y);
            a[2] = (short)f2bf16(a0.z); a[3] = (short)f2bf16(a0.w);
            a[4] = (short)f2bf16(a1.x); a[5] = (short)f2bf16(a1.y);
            a[6] = (short)f2bf16(a1.z); a[7] = (short)f2bf16(a1.w);
        }
        const int k8 = (f0 >> 3) + kq;
#pragma unroll
        for (int t = 0; t < 8; ++t) {
            const short8v b = ((const short8v*)Wl)[(k8 << 7) + 16 * t + mrow];
            acc[t] = __builtin_amdgcn_mfma_f32_16x16x32_bf16(a, b, acc[t], 0, 0, 0);
        }
    }

    // ---- epilogue: bias, bf16 store, fused al/ar ----
    float pa[4] = {0.f, 0.f, 0.f, 0.f};
    float pr[4] = {0.f, 0.f, 0.f, 0.f};
    float hb[8][4];
#pragma unroll
    for (int t = 0; t < 8; ++t) {
        const float bj = bias[16 * t + mrow];
        const float wl = alw[16 * t + mrow];
        const float wr = arw[16 * t + mrow];
#pragma unroll
        for (int g = 0; g < 4; ++g) {
            const float h = acc[t][g] + bj;
            hb[t][g] = h;
            pa[g] = fmaf(h, wl, pa[g]);
            pr[g] = fmaf(h, wr, pr[g]);
        }
    }
    // rows owned by this lane-group: r0 + 4*kq + g  (C/D layout)
    const int rbase = blockIdx.x * 64 + wid * 16 + 4 * kq;
#pragma unroll
    for (int g = 0; g < 4; ++g) {
        const int orow = rbase + g;
        if (orow < NN) {
#pragma unroll
            for (int t = 0; t < 8; ++t)
                out16[(size_t)orow * HD + 16 * t + mrow] = f2bf16(hb[t][g]);
        }
    }
    // 16-lane (col) reduction for al/ar
#pragma unroll
    for (int o = 8; o >= 1; o >>= 1) {
#pragma unroll
        for (int g = 0; g < 4; ++g) {
            pa[g] += __shfl_xor(pa[g], o, 16);
            pr[g] += __shfl_xor(pr[g], o, 16);
        }
    }
    if (mrow == 0) {
#pragma unroll
        for (int g = 0; g < 4; ++g) {
            const int orow = rbase + g;
            if (orow < NN) {
                al[orow] = pa[g] + alb[0];
                ar[orow] = pr[g] + arb[0];
            }
        }
    }
}

// ---------------------------------------------------------------------------
// Aggregation: one wave per node (block = 4 nodes). 64 lanes compute the
// 4 hops' 16-way softmaxes; inner loop gathers TWO rows per instruction
// (dwordx2: lanes 0-31 even gather, lanes 32-63 odd), 32 iterations.
// Output bf16.
// ---------------------------------------------------------------------------
__global__ __launch_bounds__(256) void aggr_kernel(
    const ushort_t* __restrict__ h16, const float* __restrict__ al,
    const float* __restrict__ ar, const int* __restrict__ ends_l,
    const float* __restrict__ att_l, ushort_t* __restrict__ out16)
{
    __shared__ uint2 ew_s[4][64];
    const int wv   = threadIdx.x >> 6;
    const int lane = threadIdx.x & 63;
    const int node = blockIdx.x * 4 + wv;
    const int k    = lane >> 4;
    const int j    = lane & 15;

    const int e = ends_l[(size_t)k * NRW + node * RWSS + j];
    float lg = al[node] + ar[e];
    lg = (lg > 0.f) ? lg : 0.2f * lg;
    float m = lg;
#pragma unroll
    for (int o = 8; o >= 1; o >>= 1) m = fmaxf(m, __shfl_xor(m, o, 16));
    const float ex = __expf(lg - m);
    float s = ex;
#pragma unroll
    for (int o = 8; o >= 1; o >>= 1) s += __shfl_xor(s, o, 16);
    uint2 ew;
    ew.x = (uint32)e;
    ew.y = __float_as_uint(ex / s * att_l[k + 1] * (1.0f / RWSS));
    ew_s[wv][lane] = ew;
    __syncthreads();

    const uint2* hp2 = (const uint2*)h16;      // 8 B = 4 bf16 channels
    const int half = lane >> 5;
    const int c4   = lane & 31;                // channels 4*c4 .. 4*c4+3
    float acc0 = 0.f, acc1 = 0.f, acc2 = 0.f, acc3 = 0.f;
#pragma unroll
    for (int i = 0; i < 32; ++i) {
        const uint2 w2 = ew_s[wv][2 * i + half];
        const uint2 v  = hp2[(size_t)w2.x * (HD / 4) + c4];
        const float wi = __uint_as_float(w2.y);
        acc0 = fmaf(bf16lo(v.x), wi, acc0);
        acc1 = fmaf(bf16hi(v.x), wi, acc1);
        acc2 = fmaf(bf16lo(v.y), wi, acc2);
        acc3 = fmaf(bf16hi(v.y), wi, acc3);
    }
    acc0 += __shfl_xor(acc0, 32, 64);
    acc1 += __shfl_xor(acc1, 32, 64);
    acc2 += __shfl_xor(acc2, 32, 64);
    acc3 += __shfl_xor(acc3, 32, 64);
    if (half == 0) {
        const uint2 vs = hp2[(size_t)node * (HD / 4) + c4];
        const float a0t = att_l[0];
        acc0 = fmaf(bf16lo(vs.x), a0t, acc0);
        acc1 = fmaf(bf16hi(vs.x), a0t, acc1);
        acc2 = fmaf(bf16lo(vs.y), a0t, acc2);
        acc3 = fmaf(bf16hi(vs.y), a0t, acc3);
        uint2 o;
        o.x = (uint32)f2bf16(acc0) | ((uint32)f2bf16(acc1) << 16);
        o.y = (uint32)f2bf16(acc2) | ((uint32)f2bf16(acc3) << 16);
        ((uint2*)out16)[(size_t)node * (HD / 4) + c4] = o;
    }
}

// ---------------------------------------------------------------------------
// out = log_softmax(h16 @ lout_w^T + lout_b).  One wave per node (C=64 lanes).
// ---------------------------------------------------------------------------
__global__ __launch_bounds__(256) void out_kernel(
    const ushort_t* __restrict__ h16, const float* __restrict__ lw,
    const float* __restrict__ lb, float* __restrict__ outp)
{
    __shared__ float ws[HD][CC + 1];   // ws[f][c]
    __shared__ float hs[4][HD];
    const int tid = threadIdx.x;
    for (int i = tid; i < CC * HD; i += 256) {
        const int ccol = i >> 7;
        const int ff   = i & 127;
        ws[ff][ccol] = lw[i];
    }
    const int w    = tid >> 6;
    const int lane = tid & 63;
    const int node = blockIdx.x * 4 + w;
    {
        const uint32 v = ((const uint32*)h16)[(size_t)node * (HD / 2) + lane];
        hs[w][2 * lane]     = bf16lo(v);
        hs[w][2 * lane + 1] = bf16hi(v);
    }
    __syncthreads();
    float acc = lb[lane];
#pragma unroll 8
    for (int f = 0; f < HD; ++f)
        acc = fmaf(hs[w][f], ws[f][lane], acc);
    float m = acc;
#pragma unroll
    for (int o = 32; o >= 1; o >>= 1) m = fmaxf(m, __shfl_xor(m, o, 64));
    const float ex = __expf(acc - m);
    float s = ex;
#pragma unroll
    for (int o = 32; o >= 1; o >>= 1) s += __shfl_xor(s, o, 64);
    outp[(size_t)node * CC + lane] = acc - m - __logf(s);
}

// ---------------------------------------------------------------------------
extern "C" void kernel_launch(void* const* d_in, const int* in_sizes, int n_in,
                              void* d_out, int out_size, void* d_ws, size_t ws_size,
                              hipStream_t stream)
{
    const float* x      = (const float*)d_in[0];
    const int*   ends   = (const int*)  d_in[1];
    const float* lin0_w = (const float*)d_in[2];
    const float* lin0_b = (const float*)d_in[3];
    const float* lin1_w = (const float*)d_in[4];
    const float* lin1_b = (const float*)d_in[5];
    const float* lout_w = (const float*)d_in[6];
    const float* lout_b = (const float*)d_in[7];
    const float* attl_w = (const float*)d_in[8];
    const float* attl_b = (const float*)d_in[9];
    const float* attr_w = (const float*)d_in[10];
    const float* attr_b = (const float*)d_in[11];
    const float* att    = (const float*)d_in[12];
    float* outp = (float*)d_out;

    // workspace
    ushort_t* h16   = (ushort_t*)d_ws;                    // 50000*128 bf16
    ushort_t* agg16 = h16 + (size_t)NN * HD;              // 50000*128 bf16
    float*    albuf = (float*)(agg16 + (size_t)NN * HD);  // 50000
    float*    arbuf = albuf + NN;                         // 50000

    const int lin_grid = (NN + 63) / 64;   // 782
    const int nb4      = NN / 4;           // 12500, exact

    // ---- layer 0 ----
    linear_mfma_kernel<FIN, false><<<lin_grid, 256, 0, stream>>>(
        x, lin0_w, lin0_b, attl_w, attl_b, attr_w, attr_b, h16, albuf, arbuf);
    aggr_kernel<<<nb4, 256, 0, stream>>>(h16, albuf, arbuf, ends, att, agg16);

    // ---- layer 1 ----
    linear_mfma_kernel<HD, true><<<lin_grid, 256, 0, stream>>>(
        agg16, lin1_w, lin1_b, attl_w + HD, attl_b + 1, attr_w + HD, attr_b + 1,
        h16, albuf, arbuf);
    aggr_kernel<<<nb4, 256, 0, stream>>>(h16, albuf, arbuf, ends + KNRW,
                                         att + (KK + 1), agg16);

    // ---- output head ----
    out_kernel<<<nb4, 256, 0, stream>>>(agg16, lout_w, lout_b, outp);
}

// Round 4
// 247.278 us; speedup vs baseline: 2.2340x; 1.1342x over previous
//
#include <hip/hip_runtime.h>

#define NN   50000
#define FIN  256
#define HD   128
#define CC   64
#define KK   4
#define RWSS 16
#define NRW  (NN*RWSS)          // 800000
#define KNRW (KK*NRW)           // 3200000

typedef unsigned int   uint32;
typedef unsigned short ushort_t;

typedef __attribute__((ext_vector_type(8))) short short8v;   // 8 bf16
typedef __attribute__((ext_vector_type(4))) float float4v;   // MFMA acc

static __device__ __forceinline__ float bf16lo(uint32 u) {
    return __uint_as_float(u << 16);
}
static __device__ __forceinline__ float bf16hi(uint32 u) {
    return __uint_as_float(u & 0xFFFF0000u);
}
static __device__ __forceinline__ ushort_t f2bf16(float f) {
    uint32 u = __float_as_uint(f);
    uint32 r = u + 0x7FFFu + ((u >> 16) & 1u);   // RNE
    return (ushort_t)(r >> 16);
}

// ---------------------------------------------------------------------------
// One-time weight conversion fp32 -> bf16 k-major 16B chunks [k8][col].
// lin0: 128x256 (4096 chunks), lin1: 128x128 (2048), lout: 64x128 (1024).
// ---------------------------------------------------------------------------
static __device__ __forceinline__ uint4 packw(const float* p) {
    const float4 w0 = *(const float4*)p;
    const float4 w1 = *(const float4*)(p + 4);
    uint4 q;
    q.x = (uint32)f2bf16(w0.x) | ((uint32)f2bf16(w0.y) << 16);
    q.y = (uint32)f2bf16(w0.z) | ((uint32)f2bf16(w0.w) << 16);
    q.z = (uint32)f2bf16(w1.x) | ((uint32)f2bf16(w1.y) << 16);
    q.w = (uint32)f2bf16(w1.z) | ((uint32)f2bf16(w1.w) << 16);
    return q;
}

__global__ __launch_bounds__(256) void prep_w_kernel(
    const float* __restrict__ w0, const float* __restrict__ w1,
    const float* __restrict__ wo,
    uint4* __restrict__ t0, uint4* __restrict__ t1, uint4* __restrict__ to_)
{
    const int idx = blockIdx.x * 256 + threadIdx.x;
    if (idx < 4096) {                       // lin0: [k8][j], j<128, k8<32
        const int jj = idx & 127, k8 = idx >> 7;
        t0[idx] = packw(w0 + (size_t)jj * FIN + 8 * k8);
    } else if (idx < 6144) {                // lin1: [k8][j], j<128, k8<16
        const int li = idx - 4096;
        const int jj = li & 127, k8 = li >> 7;
        t1[li] = packw(w1 + (size_t)jj * HD + 8 * k8);
    } else if (idx < 7168) {                // lout: [k8][c], c<64, k8<16
        const int li = idx - 6144;
        const int jj = li & 63, k8 = li >> 6;
        to_[li] = packw(wo + (size_t)jj * HD + 8 * k8);
    }
}

// ---------------------------------------------------------------------------
// MFMA linear + fused attention projections. No LDS: B-fragments straight
// from the bf16 W table (L1/L2-hot, identical addresses across blocks).
// Block = 4 waves; wave owns 16 rows x 128 cols.
// Output h16s is SLICE-MAJOR: [slice s][node][32 ch], s = ch>>5.
// ---------------------------------------------------------------------------
template<int DIN, bool ABF16>
__global__ __launch_bounds__(256) void linear_mfma_kernel(
    const void* __restrict__ Ain, const uint4* __restrict__ W16,
    const float* __restrict__ bias,
    const float* __restrict__ alw, const float* __restrict__ alb,
    const float* __restrict__ arw, const float* __restrict__ arb,
    ushort_t* __restrict__ h16s, float* __restrict__ al, float* __restrict__ ar)
{
    const int tid  = threadIdx.x;
    const int wid  = tid >> 6;
    const int lane = tid & 63;
    const int mrow = lane & 15;
    const int kq   = lane >> 4;
    const int row  = blockIdx.x * 64 + wid * 16 + mrow;
    const int arow = row < NN ? row : NN - 1;

    float4v acc[8];
#pragma unroll
    for (int t = 0; t < 8; ++t) acc[t] = (float4v){0.f, 0.f, 0.f, 0.f};

    for (int f0 = 0; f0 < DIN; f0 += 32) {
        short8v a;
        if constexpr (ABF16) {
            a = *(const short8v*)((const ushort_t*)Ain + (size_t)arow * DIN + f0 + 8 * kq);
        } else {
            const float* ap = (const float*)Ain + (size_t)arow * DIN + f0 + 8 * kq;
            const float4 a0 = *(const float4*)ap;
            const float4 a1 = *(const float4*)(ap + 4);
            a[0] = (short)f2bf16(a0.x); a[1] = (short)f2bf16(a0.y);
            a[2] = (short)f2bf16(a0.z); a[3] = (short)f2bf16(a0.w);
            a[4] = (short)f2bf16(a1.x); a[5] = (short)f2bf16(a1.y);
            a[6] = (short)f2bf16(a1.z); a[7] = (short)f2bf16(a1.w);
        }
        const int k8 = (f0 >> 3) + kq;
#pragma unroll
        for (int t = 0; t < 8; ++t) {
            const short8v b = ((const short8v*)W16)[(k8 << 7) + 16 * t + mrow];
            acc[t] = __builtin_amdgcn_mfma_f32_16x16x32_bf16(a, b, acc[t], 0, 0, 0);
        }
    }

    // ---- epilogue: bias, slice-major bf16 store, fused al/ar ----
    float pa[4] = {0.f, 0.f, 0.f, 0.f};
    float pr[4] = {0.f, 0.f, 0.f, 0.f};
    float hb[8][4];
#pragma unroll
    for (int t = 0; t < 8; ++t) {
        const float bj = bias[16 * t + mrow];
        const float wl = alw[16 * t + mrow];
        const float wr = arw[16 * t + mrow];
#pragma unroll
        for (int g = 0; g < 4; ++g) {
            const float h = acc[t][g] + bj;
            hb[t][g] = h;
            pa[g] = fmaf(h, wl, pa[g]);
            pr[g] = fmaf(h, wr, pr[g]);
        }
    }
    const int rbase = blockIdx.x * 64 + wid * 16 + 4 * kq;
#pragma unroll
    for (int g = 0; g < 4; ++g) {
        const int orow = rbase + g;
        if (orow < NN) {
#pragma unroll
            for (int t = 0; t < 8; ++t) {
                // channel c = 16t + mrow; slice = t>>1; offset = 16*(t&1)+mrow
                h16s[(size_t)(t >> 1) * (NN * 32) + (size_t)orow * 32 +
                     16 * (t & 1) + mrow] = f2bf16(hb[t][g]);
            }
        }
    }
#pragma unroll
    for (int o = 8; o >= 1; o >>= 1) {
#pragma unroll
        for (int g = 0; g < 4; ++g) {
            pa[g] += __shfl_xor(pa[g], o, 16);
            pr[g] += __shfl_xor(pr[g], o, 16);
        }
    }
    if (mrow == 0) {
#pragma unroll
        for (int g = 0; g < 4; ++g) {
            const int orow = rbase + g;
            if (orow < NN) {
                al[orow] = pa[g] + alb[0];
                ar[orow] = pr[g] + arb[0];
            }
        }
    }
}

// ---------------------------------------------------------------------------
// Pair prep: packed (w_bf16 << 16 | e) per (node, k, j). One wave per node.
// ---------------------------------------------------------------------------
__global__ __launch_bounds__(256) void prep_pairs_kernel(
    const int* __restrict__ ends_l, const float* __restrict__ al,
    const float* __restrict__ ar, const float* __restrict__ att_l,
    uint32* __restrict__ pw)
{
    const int wv   = threadIdx.x >> 6;
    const int lane = threadIdx.x & 63;
    const int node = blockIdx.x * 4 + wv;
    const int k    = lane >> 4;
    const int j    = lane & 15;

    const int e = __builtin_nontemporal_load(ends_l + (size_t)k * NRW + node * RWSS + j);
    float lg = al[node] + ar[e];
    lg = (lg > 0.f) ? lg : 0.2f * lg;
    float m = lg;
#pragma unroll
    for (int o = 8; o >= 1; o >>= 1) m = fmaxf(m, __shfl_xor(m, o, 16));
    const float ex = __expf(lg - m);
    float s = ex;
#pragma unroll
    for (int o = 8; o >= 1; o >>= 1) s += __shfl_xor(s, o, 16);
    const float w = ex / s * att_l[k + 1] * (1.0f / RWSS);
    const uint32 packed = ((uint32)f2bf16(w) << 16) | (uint32)e;   // e < 65536
    __builtin_nontemporal_store(packed, pw + (size_t)node * 64 + lane);
}

// ---------------------------------------------------------------------------
// Slice aggregation: grid (12500, 4). blockIdx.y = channel slice (32 ch,
// 3.2 MB table slice -> L2-resident). One wave per node; pairs broadcast
// via __shfl; 4 rows gathered per dword instruction (g = lane>>4).
// Output agg16 row-major bf16 (NT store).
// ---------------------------------------------------------------------------
__global__ __launch_bounds__(256) void aggr_slice_kernel(
    const ushort_t* __restrict__ h16s, const uint32* __restrict__ pw,
    const float* __restrict__ att_l, ushort_t* __restrict__ agg16)
{
    const int wv   = threadIdx.x >> 6;
    const int lane = threadIdx.x & 63;
    const int node = blockIdx.x * 4 + wv;
    const int s    = blockIdx.y;
    const uint32* h32 = (const uint32*)h16s + (size_t)s * (NN * 16);

    const uint32 p = __builtin_nontemporal_load(pw + (size_t)node * 64 + lane);
    const int g  = lane >> 4;
    const int c2 = lane & 15;

    float a0 = 0.f, a1 = 0.f;
#pragma unroll
    for (int i = 0; i < 16; ++i) {
        const uint32 pp = __shfl(p, 4 * i + g, 64);
        const uint32 e  = pp & 0xFFFFu;
        const float  w  = __uint_as_float(pp & 0xFFFF0000u);
        const uint32 v  = h32[(size_t)e * 16 + c2];
        a0 = fmaf(bf16lo(v), w, a0);
        a1 = fmaf(bf16hi(v), w, a1);
    }
    a0 += __shfl_xor(a0, 16, 64); a0 += __shfl_xor(a0, 32, 64);
    a1 += __shfl_xor(a1, 16, 64); a1 += __shfl_xor(a1, 32, 64);
    if (g == 0) {
        const uint32 v = h32[(size_t)node * 16 + c2];
        const float att0 = att_l[0];
        a0 = fmaf(bf16lo(v), att0, a0);
        a1 = fmaf(bf16hi(v), att0, a1);
        const uint32 o = (uint32)f2bf16(a0) | ((uint32)f2bf16(a1) << 16);
        __builtin_nontemporal_store(o, (uint32*)agg16 + (size_t)node * 64 + s * 16 + c2);
    }
}

// ---------------------------------------------------------------------------
// Output head: MFMA GEMM (h @ lout_w^T + b) + fused log_softmax.
// Block = 4 waves x 16 rows; 4 col-tiles of 16; 4 k-steps.
// ---------------------------------------------------------------------------
__global__ __launch_bounds__(256) void out_mfma_kernel(
    const ushort_t* __restrict__ agg16, const uint4* __restrict__ WO16,
    const float* __restrict__ lb, float* __restrict__ outp)
{
    const int tid  = threadIdx.x;
    const int wid  = tid >> 6;
    const int lane = tid & 63;
    const int mrow = lane & 15;
    const int kq   = lane >> 4;
    const int row  = blockIdx.x * 64 + wid * 16 + mrow;
    const int arow = row < NN ? row : NN - 1;

    float4v acc[4];
#pragma unroll
    for (int t = 0; t < 4; ++t) acc[t] = (float4v){0.f, 0.f, 0.f, 0.f};

#pragma unroll
    for (int f0 = 0; f0 < HD; f0 += 32) {
        const short8v a = *(const short8v*)(agg16 + (size_t)arow * HD + f0 + 8 * kq);
        const int k8 = (f0 >> 3) + kq;
#pragma unroll
        for (int t = 0; t < 4; ++t) {
            const short8v b = ((const short8v*)WO16)[(k8 << 6) + 16 * t + mrow];
            acc[t] = __builtin_amdgcn_mfma_f32_16x16x32_bf16(a, b, acc[t], 0, 0, 0);
        }
    }

    float v[4][4];
    float mx[4] = {-1e30f, -1e30f, -1e30f, -1e30f};
#pragma unroll
    for (int t = 0; t < 4; ++t) {
        const float bj = lb[16 * t + mrow];
#pragma unroll
        for (int g = 0; g < 4; ++g) {
            v[t][g] = acc[t][g] + bj;
            mx[g] = fmaxf(mx[g], v[t][g]);
        }
    }
#pragma unroll
    for (int o = 8; o >= 1; o >>= 1)
#pragma unroll
        for (int g = 0; g < 4; ++g) mx[g] = fmaxf(mx[g], __shfl_xor(mx[g], o, 16));
    float sm[4] = {0.f, 0.f, 0.f, 0.f};
#pragma unroll
    for (int t = 0; t < 4; ++t)
#pragma unroll
        for (int g = 0; g < 4; ++g) sm[g] += __expf(v[t][g] - mx[g]);
#pragma unroll
    for (int o = 8; o >= 1; o >>= 1)
#pragma unroll
        for (int g = 0; g < 4; ++g) sm[g] += __shfl_xor(sm[g], o, 16);
    float lgs[4];
#pragma unroll
    for (int g = 0; g < 4; ++g) lgs[g] = __logf(sm[g]);

    const int rbase = blockIdx.x * 64 + wid * 16 + 4 * kq;
#pragma unroll
    for (int g = 0; g < 4; ++g) {
        const int orow = rbase + g;
        if (orow < NN) {
#pragma unroll
            for (int t = 0; t < 4; ++t)
                outp[(size_t)orow * CC + 16 * t + mrow] = v[t][g] - mx[g] - lgs[g];
        }
    }
}

// ---------------------------------------------------------------------------
extern "C" void kernel_launch(void* const* d_in, const int* in_sizes, int n_in,
                              void* d_out, int out_size, void* d_ws, size_t ws_size,
                              hipStream_t stream)
{
    const float* x      = (const float*)d_in[0];
    const int*   ends   = (const int*)  d_in[1];
    const float* lin0_w = (const float*)d_in[2];
    const float* lin0_b = (const float*)d_in[3];
    const float* lin1_w = (const float*)d_in[4];
    const float* lin1_b = (const float*)d_in[5];
    const float* lout_w = (const float*)d_in[6];
    const float* lout_b = (const float*)d_in[7];
    const float* attl_w = (const float*)d_in[8];
    const float* attl_b = (const float*)d_in[9];
    const float* attr_w = (const float*)d_in[10];
    const float* attr_b = (const float*)d_in[11];
    const float* att    = (const float*)d_in[12];
    float* outp = (float*)d_out;

    // workspace layout (~39 MB)
    ushort_t* h16s  = (ushort_t*)d_ws;                    // slice-major table, 12.8MB
    ushort_t* agg16 = h16s + (size_t)NN * HD;             // row-major agg, 12.8MB
    float*    albuf = (float*)(agg16 + (size_t)NN * HD);  // 50000
    float*    arbuf = albuf + NN;                         // 50000
    uint32*   pw    = (uint32*)(arbuf + NN);              // 3.2M packed pairs, 12.8MB
    uint4*    t0    = (uint4*)(pw + (size_t)KNRW);        // 4096 chunks
    uint4*    t1    = t0 + 4096;                          // 2048 chunks
    uint4*    to_   = t1 + 2048;                          // 1024 chunks

    const int lin_grid = (NN + 63) / 64;   // 782
    const int nb4      = NN / 4;           // 12500, exact

    prep_w_kernel<<<28, 256, 0, stream>>>(lin0_w, lin1_w, lout_w, t0, t1, to_);

    // ---- layer 0 ----
    linear_mfma_kernel<FIN, false><<<lin_grid, 256, 0, stream>>>(
        x, t0, lin0_b, attl_w, attl_b, attr_w, attr_b, h16s, albuf, arbuf);
    prep_pairs_kernel<<<nb4, 256, 0, stream>>>(ends, albuf, arbuf, att, pw);
    aggr_slice_kernel<<<dim3(nb4, 4), 256, 0, stream>>>(h16s, pw, att, agg16);

    // ---- layer 1 ----
    linear_mfma_kernel<HD, true><<<lin_grid, 256, 0, stream>>>(
        agg16, t1, lin1_b, attl_w + HD, attl_b + 1, attr_w + HD, attr_b + 1,
        h16s, albuf, arbuf);
    prep_pairs_kernel<<<nb4, 256, 0, stream>>>(ends + KNRW, albuf, arbuf,
                                               att + (KK + 1), pw);
    aggr_slice_kernel<<<dim3(nb4, 4), 256, 0, stream>>>(h16s, pw, att + (KK + 1), agg16);

    // ---- output head ----
    out_mfma_kernel<<<lin_grid, 256, 0, stream>>>(agg16, to_, lout_b, outp);
}